// Round 6
// baseline (867.944 us; speedup 1.0000x reference)
//
#include <hip/hip_runtime.h>
#include <stdint.h>

// ============================================================================
// Windowed attention (SAM-style), MI355X gfx950.
// B=256, N=196 (14x14), C=768, 12 heads x 64.
// R2: GEMMs = 256x256-tile 8-wave double-buffered 8-phase (unchanged).
// R7: attn = R6 dual-q-tile online structure + ONE-HOT BIAS-IN-MFMA:
//     rel bias folded into the score MFMA via K-extension to 96:
//       q_ext[64+b]   = q . Rh[hq-b+13]  (b=0..13; Tw at 16..29)
//       k_ext[64+d]   = onehot(hk) / onehot(16+wk)   <- pure lane arithmetic
//     Removes 32 ds_read bias gathers + per-r key-coord math per 32-key step
//     (R6's LDS pipe: ~330cy/step vs 60 MFMA). TL shrinks to a per-wave
//     [2][27][16] f32 staging used once per pair -> LDS 54784 -> 40448
//     (2 -> 4 blocks/CU). brl now per-pair transient (VGPR). P packing via
//     v_cvt_pk_bf16_f32 (T12).
// ============================================================================

typedef __attribute__((ext_vector_type(8))) short bf16x8;   // 8 bf16 = 4 VGPRs
typedef __attribute__((ext_vector_type(4))) float f32x4;
typedef __attribute__((ext_vector_type(4))) unsigned int u32x4;
typedef unsigned short u16;
typedef unsigned int u32;

__device__ __forceinline__ u16 f2bf(float f) {
  u32 x = __float_as_uint(f);
  x += 0x7fffu + ((x >> 16) & 1u);   // round-to-nearest-even
  return (u16)(x >> 16);
}

__device__ __forceinline__ u32 pack2bf(float a, float b) {
  return (u32)f2bf(a) | ((u32)f2bf(b) << 16);
}

// T12 recipe: lo = bf16(a), hi = bf16(b) in one VALU op
__device__ __forceinline__ u32 cvtpk(float a, float b) {
  u32 r;
  asm("v_cvt_pk_bf16_f32 %0, %1, %2" : "=v"(r) : "v"(a), "v"(b));
  return r;
}

__device__ __forceinline__ void gload_lds16(const void* g, void* l) {
  __builtin_amdgcn_global_load_lds(
      (__attribute__((address_space(1))) void*)g,
      (__attribute__((address_space(3))) void*)l, 16, 0, 0);
}

// ---------------------------------------------------------------------------
__global__ __launch_bounds__(256) void cvt_bf16(const float* __restrict__ src,
                                                u16* __restrict__ dst, int n4) {
  int i = blockIdx.x * 256 + threadIdx.x;
  if (i < n4) {
    float4 f = ((const float4*)src)[i];
    uint2 p;
    p.x = pack2bf(f.x, f.y);
    p.y = pack2bf(f.z, f.w);
    ((uint2*)dst)[i] = p;
  }
}

// ---------------------------------------------------------------------------
// 256x256-tile bf16 GEMM, BK=64, K=768 (12 K-tiles), B^T weights.
// (unchanged from R2)
__device__ __forceinline__ void stage8(const u16* pA, const u16* pB,
                                       char* dstA, int k0) {
#pragma unroll
  for (int i = 0; i < 4; i++)
    gload_lds16(pA + (size_t)i * 49152 + k0, dstA + i * 8192);
#pragma unroll
  for (int i = 0; i < 4; i++)
    gload_lds16(pB + (size_t)i * 49152 + k0, dstA + 32768 + i * 8192);
}

template <int MODE, int NT>
__global__ __launch_bounds__(512, 2) void gemm256(
    const u16* __restrict__ A, const u16* __restrict__ W,
    const float* __restrict__ bias, u16* __restrict__ qb, u16* __restrict__ kb,
    u16* __restrict__ vb, float* __restrict__ outf) {
  __shared__ char lds[131072];   // 2 x (32KB A + 32KB B)

  const int t = threadIdx.x;
  const int lane = t & 63, wv = t >> 6;
  const int quad = lane >> 4, l15 = lane & 15;
  const int wm = wv >> 2, wn = wv & 3;   // 2 x 4 wave grid

  // ---- bijective XCD-chunked block swizzle (m204), n-tile fastest ----
  const u32 nwg = gridDim.x;
  const u32 wg = blockIdx.x;
  const u32 qd = nwg >> 3, rm = nwg & 7;
  const u32 xcd = wg & 7, loc = wg >> 3;
  const u32 swz = (xcd < rm) ? (xcd * (qd + 1) + loc)
                             : (rm * (qd + 1) + (xcd - rm) * qd + loc);
  const int mtile = swz / NT;
  const int ntile = (int)swz - mtile * NT;
  const int m0 = mtile << 8, n0 = ntile << 8;

  // ---- staging addresses (thread-constant swizzle) ----
  const int srow = t >> 3;
  const int scol = ((t & 7) ^ (srow & 7)) << 3;   // elements
  const u16* pA = A + (size_t)(m0 + srow) * 768 + scol;
  const u16* pB = W + (size_t)(n0 + srow) * 768 + scol;
  char* sdst = lds + t * 16;

  // ---- ds_read byte offsets (within current buffer) ----
  const int swz0 = ((quad) ^ (l15 & 7)) << 4;        // k-step 0
  const int swz1 = ((4 + quad) ^ (l15 & 7)) << 4;    // k-step 1
  const int arow = (wm * 128 + l15) * 128;
  const int brow = 32768 + (wn * 64 + l15) * 128;

  f32x4 acc[8][4];
#pragma unroll
  for (int i = 0; i < 8; i++)
#pragma unroll
    for (int j = 0; j < 4; j++) acc[i][j] = (f32x4){0.f, 0.f, 0.f, 0.f};

  // ---- prologue: stage tile 0 ----
  stage8(pA, pB, sdst, 0);
  asm volatile("s_waitcnt vmcnt(0)" ::: "memory");
  __builtin_amdgcn_s_barrier();

  bf16x8 af[4][2], bfr[4][2];
  for (int kt = 0; kt < 12; ++kt) {
    char* bufc = lds + ((kt & 1) << 16);
    char* nsdst = sdst + (((kt & 1) ^ 1) << 16);
    const int k0n = (kt + 1) << 6;

    // ======== P0: A rows 0-63 + B cols 0-31; stage next tile ========
#pragma unroll
    for (int mf = 0; mf < 4; mf++) {
      af[mf][0] = *(const bf16x8*)(bufc + arow + mf * 2048 + swz0);
      af[mf][1] = *(const bf16x8*)(bufc + arow + mf * 2048 + swz1);
    }
#pragma unroll
    for (int nf = 0; nf < 2; nf++) {
      bfr[nf][0] = *(const bf16x8*)(bufc + brow + nf * 2048 + swz0);
      bfr[nf][1] = *(const bf16x8*)(bufc + brow + nf * 2048 + swz1);
    }
    if (kt < 11) stage8(pA, pB, nsdst, k0n);
    __builtin_amdgcn_s_barrier();
    asm volatile("s_waitcnt lgkmcnt(0)" ::: "memory");
    __builtin_amdgcn_s_setprio(1);
#pragma unroll
    for (int k = 0; k < 2; k++)
#pragma unroll
      for (int mf = 0; mf < 4; mf++)
#pragma unroll
        for (int nf = 0; nf < 2; nf++)
          acc[mf][nf] = __builtin_amdgcn_mfma_f32_16x16x32_bf16(
              af[mf][k], bfr[nf][k], acc[mf][nf], 0, 0, 0);
    __builtin_amdgcn_s_setprio(0);
    __builtin_amdgcn_s_barrier();

    // ======== P1: B cols 32-63 ========
#pragma unroll
    for (int nf = 2; nf < 4; nf++) {
      bfr[nf][0] = *(const bf16x8*)(bufc + brow + nf * 2048 + swz0);
      bfr[nf][1] = *(const bf16x8*)(bufc + brow + nf * 2048 + swz1);
    }
    __builtin_amdgcn_s_barrier();
    asm volatile("s_waitcnt lgkmcnt(0)" ::: "memory");
    __builtin_amdgcn_s_setprio(1);
#pragma unroll
    for (int k = 0; k < 2; k++)
#pragma unroll
      for (int mf = 0; mf < 4; mf++)
#pragma unroll
        for (int nf = 2; nf < 4; nf++)
          acc[mf][nf] = __builtin_amdgcn_mfma_f32_16x16x32_bf16(
              af[mf][k], bfr[nf][k], acc[mf][nf], 0, 0, 0);
    __builtin_amdgcn_s_setprio(0);
    __builtin_amdgcn_s_barrier();

    // ======== P2: A rows 64-127 ========
#pragma unroll
    for (int mf = 0; mf < 4; mf++) {
      af[mf][0] = *(const bf16x8*)(bufc + arow + (mf + 4) * 2048 + swz0);
      af[mf][1] = *(const bf16x8*)(bufc + arow + (mf + 4) * 2048 + swz1);
    }
    __builtin_amdgcn_s_barrier();
    asm volatile("s_waitcnt lgkmcnt(0)" ::: "memory");
    __builtin_amdgcn_s_setprio(1);
#pragma unroll
    for (int k = 0; k < 2; k++)
#pragma unroll
      for (int mf = 0; mf < 4; mf++)
#pragma unroll
        for (int nf = 0; nf < 2; nf++)
          acc[mf + 4][nf] = __builtin_amdgcn_mfma_f32_16x16x32_bf16(
              af[mf][k], bfr[nf][k], acc[mf + 4][nf], 0, 0, 0);
    __builtin_amdgcn_s_setprio(0);
    __builtin_amdgcn_s_barrier();

    // ======== P3: no ds_reads; drain next-tile staging at the end ========
    __builtin_amdgcn_s_setprio(1);
#pragma unroll
    for (int k = 0; k < 2; k++)
#pragma unroll
      for (int mf = 0; mf < 4; mf++)
#pragma unroll
        for (int nf = 2; nf < 4; nf++)
          acc[mf + 4][nf] = __builtin_amdgcn_mfma_f32_16x16x32_bf16(
              af[mf][k], bfr[nf][k], acc[mf + 4][nf], 0, 0, 0);
    __builtin_amdgcn_s_setprio(0);
    asm volatile("s_waitcnt vmcnt(0)" ::: "memory");
    __builtin_amdgcn_s_barrier();
  }

  // ---- epilogue ----
  if (MODE == 0) {
    const int which = n0 / 768;   // block-uniform (256 | 768-boundaries)
    u16* dst = (which == 0) ? qb : ((which == 1) ? kb : vb);
    const float sc = (which == 0) ? 0.125f : 1.0f;
    float bs[4];
    size_t hb[4];
#pragma unroll
    for (int nf = 0; nf < 4; nf++) {
      int n = n0 + wn * 64 + nf * 16 + l15;
      int cc = n - which * 768;
      bs[nf] = bias[n];
      hb[nf] = (size_t)(cc >> 6) * 12544 + (size_t)(cc & 63);
    }
#pragma unroll
    for (int mf = 0; mf < 8; mf++) {
#pragma unroll
      for (int r = 0; r < 4; r++) {
        int m = m0 + wm * 128 + mf * 16 + (quad << 2) + r;
        int bb = m / 196;
        int tok = m - bb * 196;
        size_t rb = (size_t)bb * 150528 + (size_t)tok * 64;
#pragma unroll
        for (int nf = 0; nf < 4; nf++)
          dst[rb + hb[nf]] = f2bf((acc[mf][nf][r] + bs[nf]) * sc);
      }
    }
  } else {
    float bs[4];
#pragma unroll
    for (int nf = 0; nf < 4; nf++)
      bs[nf] = bias[n0 + wn * 64 + nf * 16 + l15];
#pragma unroll
    for (int mf = 0; mf < 8; mf++) {
#pragma unroll
      for (int r = 0; r < 4; r++) {
        int m = m0 + wm * 128 + mf * 16 + (quad << 2) + r;
#pragma unroll
        for (int nf = 0; nf < 4; nf++)
          outf[(size_t)m * 768 + (n0 + wn * 64 + nf * 16 + l15)] =
              acc[mf][nf][r] + bs[nf];
      }
    }
  }
}

// ---------------------------------------------------------------------------
// Fused attention, swapped-operand, online score->PV, dual q-tile per wave,
// rel bias folded into the score MFMA (K-ext to 96 with one-hot k side).
//
// Score: S^T = mfma(K,Q) + mfma(K_1hot, Q_ext): lane&15 = qrow (C col),
// key = quad*4+r (C row). Q_ext[qrow][d]: d 0..13 = Th[b=d] = q.Rh[hq-d+13],
// d 16..29 = Tw[b=d-16]; built once per pair via T^T mfmas -> TL staging ->
// 8 scalar reads -> bf16x8 A..B-frag. K_1hot[key][d] = 1.0 at d=hk, 16+wk:
// pure lane arithmetic per 16-key tile.
// LDS = 26624 (Vt) + 13824 (TL [4][2][27][16] f32) = 40448 -> 4 blocks/CU.
__global__ __launch_bounds__(256) void attn_fused(
    const u16* __restrict__ qbuf, const u16* __restrict__ kbuf,
    const u16* __restrict__ vbuf, const float* __restrict__ rel_h,
    const float* __restrict__ rel_w, u16* __restrict__ aout) {
  __shared__ u16 Vt[26 * 512];        // 26 chunks x [64 d][8 keys] = 26624 B
  __shared__ float TL[4][2][27][16];  // per-wave T^T staging: 13824 B

  const int t = threadIdx.x;
  const int bh = blockIdx.x;
  const int b = bh / 12, h = bh - b * 12;
  const int lane = t & 63, wv = t >> 6;
  const int quad = lane >> 4, l15 = lane & 15;
  const size_t base = (size_t)bh * (196 * 64);

  // ---- stage V^T (chunked); write order rotated by seg (bank-spread) ----
  for (int c = t; c < 196 * 8; c += 256) {
    int row = c >> 3, seg = c & 7;    // key row, d-segment
    uint4 vv = *(const uint4*)(vbuf + base + row * 64 + seg * 8);
    const u16* pv8 = (const u16*)&vv;
    u16* dst = Vt + (row >> 3) * 512 + (row & 7);
#pragma unroll
    for (int e = 0; e < 8; e++) {
      int ee = (e + seg) & 7;
      dst[(seg * 8 + ee) * 8] = pv8[ee];
    }
  }
  // zero keys 196..207 (chunks 24,25 tails) so PV never multiplies NaN bits
  for (int i = t; i < 12 * 64; i += 256) {
    int k = 196 + (i >> 6), d = i & 63;
    Vt[(k >> 3) * 512 + d * 8 + (k & 7)] = 0;
  }
  __syncthreads();   // Vt ready (only barrier)

  const u16* kB = kbuf + base;
  const u16* qB = qbuf + base;

  // ---- dual q-tile pairs ----
  for (int p = wv; p < 7; p += 4) {
    const int qt0 = 2 * p;

    bf16x8 aq0[2], aq1[2], aq2[2];
    int hqv[2], wqv[2];
#pragma unroll
    for (int j = 0; j < 2; j++) {
      int qrl = (qt0 + j) * 16 + l15;
      if (qrl > 195) qrl = 195;
      aq0[j] = *(const bf16x8*)(qB + qrl * 64 + quad * 8);
      aq1[j] = *(const bf16x8*)(qB + qrl * 64 + 32 + quad * 8);
      hqv[j] = qrl / 14;
      wqv[j] = qrl - hqv[j] * 14;
    }

    // rel frags (transient; f32 rel tables are L1/L2-hot, 13.8KB)
    // lane holds Rel[nt*16+l15][ks*32 + quad*8 + e]
    bf16x8 brl[2][2][2];
#pragma unroll
    for (int half = 0; half < 2; half++) {
      const float* relp = half ? rel_w : rel_h;
#pragma unroll
      for (int nt = 0; nt < 2; nt++) {
        int ridx = nt * 16 + l15;
        if (ridx > 26) ridx = 26;     // dup; rows >=27 never stored
#pragma unroll
        for (int ks = 0; ks < 2; ks++) {
          const float* pf = relp + ridx * 64 + ks * 32 + quad * 8;
          float4 f0 = *(const float4*)pf;
          float4 f1 = *(const float4*)(pf + 4);
          u32x4 rr = (u32x4){cvtpk(f0.x, f0.y), cvtpk(f0.z, f0.w),
                             cvtpk(f1.x, f1.y), cvtpk(f1.z, f1.w)};
          brl[half][nt][ks] = __builtin_bit_cast(bf16x8, rr);
        }
      }
    }

    // T^T = mfma(rel, q) -> TL (col=l15=qrow, row=r27), then gather Q_ext
#pragma unroll
    for (int j = 0; j < 2; j++) {
#pragma unroll
      for (int half = 0; half < 2; half++) {
#pragma unroll
        for (int nt = 0; nt < 2; nt++) {
          f32x4 tc = (f32x4){0.f, 0.f, 0.f, 0.f};
          tc = __builtin_amdgcn_mfma_f32_16x16x32_bf16(brl[half][nt][0], aq0[j], tc, 0, 0, 0);
          tc = __builtin_amdgcn_mfma_f32_16x16x32_bf16(brl[half][nt][1], aq1[j], tc, 0, 0, 0);
#pragma unroll
          for (int r = 0; r < 4; r++) {
            int r27 = nt * 16 + quad * 4 + r;
            if (r27 < 27) TL[wv][half][r27][l15] = tc[r];
          }
        }
      }
      // Q_ext B-frag: element d = quad*8+e; d<16 -> Th[b=(quad&1)*8+e],
      // d>=16 -> Tw[b]; b>13 -> 0. Value = TL[half][cc-b+13][l15].
      const int hf = quad >> 1;
      const int cc = (quad < 2) ? hqv[j] : wqv[j];
      u32 w4[4];
#pragma unroll
      for (int wd = 0; wd < 4; wd++) {
        int bb0 = (quad & 1) * 8 + wd * 2;
        int bb1 = bb0 + 1;
        float v0 = (bb0 < 14) ? TL[wv][hf][cc - bb0 + 13][l15] : 0.f;
        float v1 = (bb1 < 14) ? TL[wv][hf][cc - bb1 + 13][l15] : 0.f;
        w4[wd] = cvtpk(v0, v1);
      }
      aq2[j] = __builtin_bit_cast(bf16x8, (u32x4){w4[0], w4[1], w4[2], w4[3]});
    }

    // ---- online score+PV: 6 mask-free 32-key steps, dual chains ----
    f32x4 oacc[2][4];
#pragma unroll
    for (int j = 0; j < 2; j++)
#pragma unroll
      for (int dt = 0; dt < 4; dt++) oacc[j][dt] = (f32x4){0.f, 0.f, 0.f, 0.f};
    float sm[2] = {0.f, 0.f};
    const int srcA = l15 + ((quad & 1) << 5);
    const bool hi = (quad >> 1) != 0;
    const int d0q = quad * 8;

    for (int st = 0; st < 6; st++) {
      u32 pw[2][2][2];   // [j][u][word]
#pragma unroll
      for (int u = 0; u < 2; u++) {
        const int kt = st * 2 + u;
        const int keyl = kt * 16 + l15;            // <= 191: no clamp
        bf16x8 bk0 = *(const bf16x8*)(kB + keyl * 64 + quad * 8);
        bf16x8 bk1 = *(const bf16x8*)(kB + keyl * 64 + 32 + quad * 8);
        const int hk = keyl / 14;
        const int wk16 = 16 + (keyl - 14 * hk);
        u32 b2[4];
#pragma unroll
        for (int wd = 0; wd < 4; wd++) {
          int d = d0q + wd * 2;
          u32 lo = (d == hk || d == wk16) ? 0x3F80u : 0u;
          u32 hh = (d + 1 == hk || d + 1 == wk16) ? 0x3F80u : 0u;
          b2[wd] = lo | (hh << 16);
        }
        bf16x8 bk2 = __builtin_bit_cast(bf16x8, (u32x4){b2[0], b2[1], b2[2], b2[3]});
#pragma unroll
        for (int j = 0; j < 2; j++) {
          f32x4 s = (f32x4){0.f, 0.f, 0.f, 0.f};
          s = __builtin_amdgcn_mfma_f32_16x16x32_bf16(bk0, aq0[j], s, 0, 0, 0);
          s = __builtin_amdgcn_mfma_f32_16x16x32_bf16(bk1, aq1[j], s, 0, 0, 0);
          s = __builtin_amdgcn_mfma_f32_16x16x32_bf16(bk2, aq2[j], s, 0, 0, 0);
          float p0 = __expf(s[0]), p1 = __expf(s[1]);
          float p2 = __expf(s[2]), p3 = __expf(s[3]);
          sm[j] += (p0 + p1) + (p2 + p3);
          pw[j][u][0] = cvtpk(p0, p1);
          pw[j][u][1] = cvtpk(p2, p3);
        }
      }
      // transpose each tile's P into its PV B-frag (8 shfl + 4 sel per j)
      bf16x8 pb[2];
#pragma unroll
      for (int j = 0; j < 2; j++) {
        u32 a0 = __shfl(pw[j][0][0], srcA),      b0 = __shfl(pw[j][1][0], srcA);
        u32 a1 = __shfl(pw[j][0][1], srcA),      b1 = __shfl(pw[j][1][1], srcA);
        u32 a2 = __shfl(pw[j][0][0], srcA + 16), b2 = __shfl(pw[j][1][0], srcA + 16);
        u32 a3 = __shfl(pw[j][0][1], srcA + 16), b3 = __shfl(pw[j][1][1], srcA + 16);
        u32x4 pbw = (u32x4){hi ? b0 : a0, hi ? b1 : a1, hi ? b2 : a2, hi ? b3 : a3};
        pb[j] = __builtin_bit_cast(bf16x8, pbw);
      }
#pragma unroll
      for (int dt = 0; dt < 4; dt++) {
        bf16x8 av = *(const bf16x8*)(Vt + (st * 4 + quad) * 512 + (dt * 16 + l15) * 8);
#pragma unroll
        for (int j = 0; j < 2; j++)
          oacc[j][dt] = __builtin_amdgcn_mfma_f32_16x16x32_bf16(av, pb[j], oacc[j][dt], 0, 0, 0);
      }
    }

    // ---- tail: kt = 12 (keys 192..195 valid; rest masked) ----
    {
      const int keyl = 192 + l15;
      const int keyc = (keyl > 195) ? 195 : keyl;
      bf16x8 bk0 = *(const bf16x8*)(kB + keyc * 64 + quad * 8);
      bf16x8 bk1 = *(const bf16x8*)(kB + keyc * 64 + 32 + quad * 8);
      const int hk = keyc / 14;
      const int wk16 = 16 + (keyc - 14 * hk);
      u32 b2[4];
#pragma unroll
      for (int wd = 0; wd < 4; wd++) {
        int d = d0q + wd * 2;
        u32 lo = (d == hk || d == wk16) ? 0x3F80u : 0u;
        u32 hh = (d + 1 == hk || d + 1 == wk16) ? 0x3F80u : 0u;
        b2[wd] = lo | (hh << 16);
      }
      bf16x8 bk2 = __builtin_bit_cast(bf16x8, (u32x4){b2[0], b2[1], b2[2], b2[3]});
      const bool valid = (quad == 0);   // output keys = quad*4+r; 192..195 only
      u32 pwt[2][2];
#pragma unroll
      for (int j = 0; j < 2; j++) {
        f32x4 s = (f32x4){0.f, 0.f, 0.f, 0.f};
        s = __builtin_amdgcn_mfma_f32_16x16x32_bf16(bk0, aq0[j], s, 0, 0, 0);
        s = __builtin_amdgcn_mfma_f32_16x16x32_bf16(bk1, aq1[j], s, 0, 0, 0);
        s = __builtin_amdgcn_mfma_f32_16x16x32_bf16(bk2, aq2[j], s, 0, 0, 0);
        float pr[4];
#pragma unroll
        for (int r = 0; r < 4; r++) {
          float pe = valid ? __expf(s[r]) : 0.f;
          pr[r] = pe;
          sm[j] += pe;
        }
        pwt[j][0] = cvtpk(pr[0], pr[1]);
        pwt[j][1] = cvtpk(pr[2], pr[3]);
      }
      bf16x8 pb[2];
#pragma unroll
      for (int j = 0; j < 2; j++) {
        u32 a0 = __shfl(pwt[j][0], srcA);
        u32 a1 = __shfl(pwt[j][1], srcA);
        u32 a2 = __shfl(pwt[j][0], srcA + 16);
        u32 a3 = __shfl(pwt[j][1], srcA + 16);
        u32x4 pbw = (u32x4){hi ? 0u : a0, hi ? 0u : a1, hi ? 0u : a2, hi ? 0u : a3};
        pb[j] = __builtin_bit_cast(bf16x8, pbw);
      }
#pragma unroll
      for (int dt = 0; dt < 4; dt++) {
        bf16x8 av = (bf16x8){0, 0, 0, 0, 0, 0, 0, 0};
        if (quad < 2)
          av = *(const bf16x8*)(Vt + (24 + quad) * 512 + (dt * 16 + l15) * 8);
#pragma unroll
        for (int j = 0; j < 2; j++)
          oacc[j][dt] = __builtin_amdgcn_mfma_f32_16x16x32_bf16(av, pb[j], oacc[j][dt], 0, 0, 0);
      }
    }

    // ---- row sums, normalize, store per tile ----
#pragma unroll
    for (int j = 0; j < 2; j++) {
      float smj = sm[j];
      smj += __shfl_xor(smj, 16, 64);
      smj += __shfl_xor(smj, 32, 64);
      const float inv = 1.0f / smj;
      const int qrow = (qt0 + j) * 16 + l15;
      if (qrow < 196) {
        u16* op = aout + ((size_t)(b * 196 + qrow) * 12 + h) * 64;
#pragma unroll
        for (int dt = 0; dt < 4; dt++) {
          uint2 stv;
          stv.x = pack2bf(oacc[j][dt][0] * inv, oacc[j][dt][1] * inv);
          stv.y = pack2bf(oacc[j][dt][2] * inv, oacc[j][dt][3] * inv);
          *(uint2*)(op + dt * 16 + quad * 4) = stv;
        }
      }
    }
  }
}

// ---------------------------------------------------------------------------
extern "C" void kernel_launch(void* const* d_in, const int* in_sizes, int n_in,
                              void* d_out, int out_size, void* d_ws, size_t ws_size,
                              hipStream_t stream) {
  (void)in_sizes; (void)n_in; (void)out_size; (void)ws_size;
  const float* x      = (const float*)d_in[0];
  const float* qkv_w  = (const float*)d_in[1];
  const float* qkv_b  = (const float*)d_in[2];
  const float* rel_h  = (const float*)d_in[3];
  const float* rel_w  = (const float*)d_in[4];
  const float* proj_w = (const float*)d_in[5];
  const float* proj_b = (const float*)d_in[6];
  float* out = (float*)d_out;

  char* ws = (char*)d_ws;
  u16* xbf  = (u16*)(ws);              // aliased: x_bf16, then attn_out
  u16* qbuf = (u16*)(ws + 77070336);
  u16* kbuf = (u16*)(ws + 154140672);
  u16* vbuf = (u16*)(ws + 231211008);
  u16* wqb  = (u16*)(ws + 308281344);
  u16* wpb  = (u16*)(ws + 311820288);

  cvt_bf16<<<37632, 256, 0, stream>>>(x, xbf, 38535168 / 4);
  cvt_bf16<<<1728, 256, 0, stream>>>(qkv_w, wqb, 1769472 / 4);
  cvt_bf16<<<576, 256, 0, stream>>>(proj_w, wpb, 589824 / 4);

  // QKV: M=50176 (196 tiles), N=2304 (9 tiles), K=768
  gemm256<0, 9><<<1764, 512, 0, stream>>>(xbf, wqb, qkv_b, qbuf, kbuf, vbuf,
                                          nullptr);
  attn_fused<<<3072, 256, 0, stream>>>(qbuf, kbuf, vbuf, rel_h, rel_w, xbf);
  // proj: N=768 (3 tiles)
  gemm256<1, 3><<<588, 512, 0, stream>>>(xbf, wpb, proj_b, nullptr, nullptr,
                                         nullptr, out);
}